// Round 8
// baseline (445.432 us; speedup 1.0000x reference)
//
#include <hip/hip_runtime.h>
#include <hip/hip_bf16.h>

// ArmaCell: B=1024, K=256, UNITS=32, P=4, Q=4
// out[b, j*32+u] = sum_{i,p} inputs[b,i*4+p]*kernel[p,u,i,j]
//                + sum_{i,q} state[b,(i*32+u)*4+q]*rk[q,u,i,j]
// out_state[b,n,:] = { out[b,n], state[b,n,0..2] }
//
// R6 (resubmit after infra failure): delete the At_ma pipeline (329MB of
// traffic: state read 128 + At_ma write 67 + GEMM re-read 134). The XCD
// swizzle puts u in [4*xcd,4*xcd+4) on one XCD; 4 consecutive u's share each
// 64B state line (col=i*128+u*4+q), and all 128 blocks of an XCD are
// co-resident -> GEMM reads state DIRECTLY: each line HBM-fetched once,
// L2-served to the 7 other sharers (4u x 2jb). prep_all shrinks to W+AR
// (9KB LDS). Workspace 69MB.

typedef __attribute__((ext_vector_type(8))) short bf16x8;
typedef __attribute__((ext_vector_type(4))) float f32x4;

__device__ inline unsigned short f2bf(float x) {
    unsigned int u = __float_as_uint(x);
    return (unsigned short)((u + 0x7fffu + ((u >> 16) & 1u)) >> 16);
}

__device__ inline void cvt_store4(unsigned short* dst, float4 v) {
    float2 ab; ab.x = v.x; ab.y = v.y;
    float2 cd; cd.x = v.z; cd.y = v.w;
    __hip_bfloat162 lo = __float22bfloat162_rn(ab);   // v_cvt_pk_bf16_f32
    __hip_bfloat162 hi = __float22bfloat162_rn(cd);
    union { __hip_bfloat162 h2[2]; uint2 u2; } pk;
    pk.h2[0] = lo; pk.h2[1] = hi;
    *(uint2*)dst = pk.u2;
}

__device__ inline void cvt_store2(unsigned short* dst, float4 v) {
    // store v.x..v.w as 4 bf16 (8B)
    float2 ab; ab.x = v.x; ab.y = v.y;
    float2 cd; cd.x = v.z; cd.y = v.w;
    __hip_bfloat162 lo = __float22bfloat162_rn(ab);
    __hip_bfloat162 hi = __float22bfloat162_rn(cd);
    union { __hip_bfloat162 h2[2]; uint2 u2; } pk;
    pk.h2[0] = lo; pk.h2[1] = hi;
    *(uint2*)dst = pk.u2;
}

// ================= R6 PATH ====================================
// Workspace layout (bytes):
//   Wtt  : [32 u][2 jb][64 kt][128 j][32 k] bf16   = 33,554,432
//   At_ar: [16 mb][32 kt][64 b][32 k] bf16         =  2,097,152   (k 0..1023)
//   Ct   : [32 u][1024 b][256 j] fp32              = 33,554,432
// total 69,206,016

// ---- prep_all: W-prep [0,4096) + AR-prep [4096,4608)
__global__ __launch_bounds__(256) void prep_all(
    const float* __restrict__ kern,     // (4,32,256,256) [p][u][i][j]
    const float* __restrict__ rkern,    // (4,32,256,256) [q][u][i][j]
    const float* __restrict__ inputs,   // (1024,1024)
    unsigned short* __restrict__ Wtt,   // (32,2,64,128,32)
    unsigned short* __restrict__ At_ar) // (16,32,64,32)
{
    __shared__ unsigned short T[64 * 72];   // [j][kk], pitch 72 (9KB)
    const int bid = blockIdx.x;
    const int t = threadIdx.x;

    if (bid < 4096) {
        // ---------------- W prep, grid (32u, 4jy, 32zz)
        const int u  = bid & 31;
        const int jy = (bid >> 5) & 3;
        const int zz = bid >> 7;           // 0..31
        const int j0 = jy * 64;
        const int mm = zz >> 4;            // 0=kern, 1=rkern
        const int it = zz & 15;            // i-tile (16 i's -> 64 k's)
        const float* src = mm ? rkern : kern;
        const int kout = mm * 1024 + it * 64;

        const int jq = t & 3;
        const int ii = (t >> 2) & 15;
        const int pp = t >> 6;             // wave-uniform
        const int i  = it * 16 + ii;
        const int kk = ii * 4 + pp;        // 0..63
        const float* row = src + ((size_t)((pp * 32 + u) * 256 + i)) * 256 + j0 + jq * 16;
        #pragma unroll
        for (int s = 0; s < 4; ++s) {
            float4 v = *(const float4*)(row + s * 4);
            const int jb_ = jq * 16 + s * 4;
            T[(jb_ + 0) * 72 + kk] = f2bf(v.x);
            T[(jb_ + 1) * 72 + kk] = f2bf(v.y);
            T[(jb_ + 2) * 72 + kk] = f2bf(v.z);
            T[(jb_ + 3) * 72 + kk] = f2bf(v.w);
        }
        __syncthreads();
        const int j = t >> 2, q = t & 3;
        const int kglob = kout + q * 16;
        const int kt  = kglob >> 5;
        const int kk0 = kglob & 31;
        const int jbo = jy >> 1;
        const int jloc = (jy & 1) * 64 + j;
        unsigned short* dst = Wtt +
            ((((size_t)(u * 2 + jbo) * 64 + kt) * 128 + jloc) * 32 + kk0);
        uint4 a = *(uint4*)&T[j * 72 + q * 16];
        uint4 b = *(uint4*)&T[j * 72 + q * 16 + 8];
        *(uint4*)dst = a;
        *(uint4*)(dst + 8) = b;
    } else {
        // ---------------- AR prep (inputs -> At_ar, 4MB read, coalesced)
        const int b2 = bid - 4096;
        const size_t e = ((size_t)b2 * 256 + t) * 8;
        const int b = (int)(e >> 10), k = (int)(e & 1023);
        float4 v0 = *(const float4*)(inputs + e);
        float4 v1 = *(const float4*)(inputs + e + 4);
        const int mb = b >> 6, row = b & 63, kt = k >> 5, kk = k & 31;
        unsigned short* d = At_ar + (((size_t)(mb * 32 + kt) * 64 + row) * 32 + kk);
        cvt_store4(d, v0);
        cvt_store4(d + 4, v1);
    }
}

// ---- GEMM: 1D grid 1024, XCD-swizzled; 64x128 tile, BK=32, dbuf.
// MA phase reads state DIRECTLY (16B chunks; lines shared by u-group on XCD).
#define PITCH 40   // bf16 pitch: 80B rows -> 2-way LDS aliasing only (free)

__global__ __launch_bounds__(256, 4) void arma_gemm_mfma3(
    const unsigned short* __restrict__ At_ar,   // (16,32,64,32) bf16
    const float* __restrict__ state,            // (1024,32768) fp32
    const unsigned short* __restrict__ Wtt,     // (32,2,64,128,32) bf16
    float* __restrict__ Ct)                     // (32,1024,256)
{
    // XCD swizzle: bid%8 = XCD (round-robin dispatch). Each XCD gets pairs
    // [8*xcd, 8*xcd+8) = u in [4*xcd, 4*xcd+4) x jb -- the 4 u's that share
    // each 64B state line. All 16 mb-blocks of a pair share L2 for Wtt.
    const int bid  = blockIdx.x;
    const int xcd  = bid & 7;
    const int slot = bid >> 3;           // 0..127
    const int pair = xcd * 8 + (slot & 7);   // 0..63
    const int mb   = slot >> 3;          // 0..15
    const int u    = pair >> 1;
    const int jb   = pair & 1;
    const int b0 = mb * 64;
    const int j0 = jb * 128;
    const int t  = threadIdx.x;
    const int lane = t & 63;
    const int wn = (t >> 6) * 32;
    const int fm = lane & 15;
    const int kq = lane >> 4;

    __shared__ unsigned short Asr[2][64 * PITCH];
    __shared__ unsigned short Wsr[2][128 * PITCH];

    const int ar_row = t >> 2, ar_off = (t & 3) * 8;
    const int w_row  = t >> 1, w_off  = (t & 1) * 16;

    // MA staging map: 512 chunks of 16B = (row 0..63, ic 0..7); thread t
    // handles chunks t (rows 0..31) and t+256 (rows 32..63).
    const int row0 = t >> 3,        ic0 = t & 7;
    const int row1 = (t >> 3) + 32, ic1 = t & 7;

    f32x4 acc[4][2];
    #pragma unroll
    for (int a = 0; a < 4; ++a)
        #pragma unroll
        for (int b = 0; b < 2; ++b)
            acc[a][b] = (f32x4)0.0f;

    const unsigned short* abase_ar = At_ar + (size_t)mb * 32 * 2048 + t * 8;
    const unsigned short* wbase    = Wtt + (size_t)(u * 2 + jb) * 64 * 4096 + t * 16;
    // state addr for (b0+row, i=ktp*8+ic, u, q=0..3); step per ktp = 1024 floats
    const float* st0 = state + (size_t)(b0 + row0) * 32768 + u * 4 + ic0 * 128;
    const float* st1 = state + (size_t)(b0 + row1) * 32768 + u * 4 + ic1 * 128;

    uint4 av, w0, w1;
    float4 ma0, ma1;

    auto LOADW = [&](int kt) {
        const unsigned short* tw = wbase + (size_t)kt * 4096;
        w0 = *(const uint4*)tw;
        w1 = *(const uint4*)(tw + 8);
    };
    auto STORE_AR = [&](int buf) {
        *(uint4*)&Asr[buf][ar_row * PITCH + ar_off] = av;
        unsigned short* wd = &Wsr[buf][w_row * PITCH + w_off];
        *(uint4*)wd = w0;
        *(uint4*)(wd + 8) = w1;
    };
    auto STORE_MA = [&](int buf) {
        cvt_store2(&Asr[buf][row0 * PITCH + ic0 * 4], ma0);
        cvt_store2(&Asr[buf][row1 * PITCH + ic1 * 4], ma1);
        unsigned short* wd = &Wsr[buf][w_row * PITCH + w_off];
        *(uint4*)wd = w0;
        *(uint4*)(wd + 8) = w1;
    };
    auto COMPUTE = [&](int buf) {
        bf16x8 af[4], bfr[2];
        #pragma unroll
        for (int mt = 0; mt < 4; ++mt)
            af[mt] = *(const bf16x8*)&Asr[buf][(mt * 16 + fm) * PITCH + kq * 8];
        #pragma unroll
        for (int nt = 0; nt < 2; ++nt)
            bfr[nt] = *(const bf16x8*)&Wsr[buf][(wn + nt * 16 + fm) * PITCH + kq * 8];
        #pragma unroll
        for (int mt = 0; mt < 4; ++mt)
            #pragma unroll
            for (int nt = 0; nt < 2; ++nt)
                acc[mt][nt] = __builtin_amdgcn_mfma_f32_16x16x32_bf16(
                    af[mt], bfr[nt], acc[mt][nt], 0, 0, 0);
    };

    // prologue: tile 0 (AR)
    av = *(const uint4*)abase_ar;
    LOADW(0);
    STORE_AR(0);
    __syncthreads();

    int cur = 0;
    // AR main: tiles 1..31 prefetched while computing 0..30
    for (int kt = 0; kt < 31; ++kt) {
        av = *(const uint4*)(abase_ar + (size_t)(kt + 1) * 2048);
        LOADW(kt + 1);
        COMPUTE(cur);
        STORE_AR(cur ^ 1);
        __syncthreads();
        cur ^= 1;
    }
    // transition + MA main: tiles 32..63 (ktp = kt-32), direct state loads
    for (int kt = 31; kt < 63; ++kt) {
        const int ktp = kt + 1 - 32;           // 0..31
        ma0 = *(const float4*)(st0 + (size_t)ktp * 1024);
        ma1 = *(const float4*)(st1 + (size_t)ktp * 1024);
        LOADW(kt + 1);
        COMPUTE(cur);
        STORE_MA(cur ^ 1);
        __syncthreads();
        cur ^= 1;
    }
    COMPUTE(cur);

    // Epilogue: contiguous Ct[u][b][j]; 16 fm-lanes -> 64B runs, no line sharing
    #pragma unroll
    for (int mt = 0; mt < 4; ++mt) {
        const int rbase = b0 + mt * 16 + kq * 4;
        #pragma unroll
        for (int nt = 0; nt < 2; ++nt) {
            const int col = j0 + wn + nt * 16 + fm;
            float* op = Ct + (size_t)u * 262144 + (size_t)rbase * 256 + col;
            op[0]       = acc[mt][nt][0];
            op[256]     = acc[mt][nt][1];
            op[2 * 256] = acc[mt][nt][2];
            op[3 * 256] = acc[mt][nt][3];
        }
    }
}

// ---- assemble3: Ct -> out (contiguous rows via LDS transpose) + out_state
__global__ __launch_bounds__(256) void arma_assemble3(
    const float* __restrict__ state,    // (1024, 32768)
    const float* __restrict__ Ct,       // (32, 1024, 256)
    float* __restrict__ out,            // (1024, 8192)
    float* __restrict__ out_state)      // (1024, 8192, 4)
{
    const int b = blockIdx.x;
    const int t = threadIdx.x;
    __shared__ float L[256 * 33];       // [j][u], pitch 33: conflict-free both ways
    for (int u = 0; u < 32; ++u)
        L[t * 33 + u] = Ct[((size_t)u * 1024 + b) * 256 + t];
    __syncthreads();
    const float* srow = state + (size_t)b * 32768;
    float* orow  = out + (size_t)b * 8192;
    float* osrow = out_state + (size_t)b * 32768;
    for (int w = 0; w < 32; ++w) {
        const int n = w * 256 + t;
        const float o = L[(n >> 5) * 33 + (n & 31)];
        const f32x4 s = *(const f32x4*)(srow + (size_t)n * 4);
        __builtin_nontemporal_store(o, orow + n);
        f32x4 rv = { o, s[0], s[1], s[2] };
        __builtin_nontemporal_store(rv, (f32x4*)(osrow + (size_t)n * 4));
    }
}

// ================= fp32 fallback (any ws size) =====================
#define BM 64
#define BN 64
#define BKF 16
#define LDP 68

__global__ __launch_bounds__(256) void arma_gemm_f32(
    const float* __restrict__ inputs, const float* __restrict__ state,
    const float* __restrict__ kern, const float* __restrict__ rkern,
    float* __restrict__ out)
{
    const int u = blockIdx.z, b0 = blockIdx.x * BM, j0 = blockIdx.y * BN;
    const int tid = threadIdx.x;
    __shared__ float As[BKF][LDP];
    __shared__ float Ws[BKF][LDP];
    const int tx = tid & 15, ty = tid >> 4;
    const int arow = tid >> 2, ak4 = (tid & 3) * 4;
    const int wrow = tid >> 4, wj = (tid & 15) * 4;
    float acc[4][4] = {{0.f}};
    for (int kt = 0; kt < 1024; kt += BKF) {
        const float4 av = *(const float4*)(inputs + (size_t)(b0 + arow) * 1024 + kt + ak4);
        As[ak4 + 0][arow] = av.x; As[ak4 + 1][arow] = av.y;
        As[ak4 + 2][arow] = av.z; As[ak4 + 3][arow] = av.w;
        const int ip = kt + wrow;
        const float4 wv = *(const float4*)(kern + ((size_t)(((ip & 3) * 32 + u) * 256 + (ip >> 2))) * 256 + j0 + wj);
        *(float4*)&Ws[wrow][wj] = wv;
        __syncthreads();
        #pragma unroll
        for (int kk = 0; kk < BKF; ++kk) {
            const float4 a4 = *(const float4*)&As[kk][ty * 4];
            const float4 w4 = *(const float4*)&Ws[kk][tx * 4];
            acc[0][0] += a4.x * w4.x; acc[0][1] += a4.x * w4.y; acc[0][2] += a4.x * w4.z; acc[0][3] += a4.x * w4.w;
            acc[1][0] += a4.y * w4.x; acc[1][1] += a4.y * w4.y; acc[1][2] += a4.y * w4.z; acc[1][3] += a4.y * w4.w;
            acc[2][0] += a4.z * w4.x; acc[2][1] += a4.z * w4.y; acc[2][2] += a4.z * w4.z; acc[2][3] += a4.z * w4.w;
            acc[3][0] += a4.w * w4.x; acc[3][1] += a4.w * w4.y; acc[3][2] += a4.w * w4.z; acc[3][3] += a4.w * w4.w;
        }
        __syncthreads();
    }
    for (int kt = 0; kt < 1024; kt += BKF) {
        const int i = (kt >> 2) + (tid & 3);
        const float4 av = *(const float4*)(state + (size_t)(b0 + arow) * 32768 + (size_t)(i * 32 + u) * 4);
        As[ak4 + 0][arow] = av.x; As[ak4 + 1][arow] = av.y;
        As[ak4 + 2][arow] = av.z; As[ak4 + 3][arow] = av.w;
        const int iq = kt + wrow;
        const float4 wv = *(const float4*)(rkern + ((size_t)(((iq & 3) * 32 + u) * 256 + (iq >> 2))) * 256 + j0 + wj);
        *(float4*)&Ws[wrow][wj] = wv;
        __syncthreads();
        #pragma unroll
        for (int kk = 0; kk < BKF; ++kk) {
            const float4 a4 = *(const float4*)&As[kk][ty * 4];
            const float4 w4 = *(const float4*)&Ws[kk][tx * 4];
            acc[0][0] += a4.x * w4.x; acc[0][1] += a4.x * w4.y; acc[0][2] += a4.x * w4.z; acc[0][3] += a4.x * w4.w;
            acc[1][0] += a4.y * w4.x; acc[1][1] += a4.y * w4.y; acc[1][2] += a4.y * w4.z; acc[1][3] += a4.y * w4.w;
            acc[2][0] += a4.z * w4.x; acc[2][1] += a4.z * w4.y; acc[2][2] += a4.z * w4.z; acc[2][3] += a4.z * w4.w;
            acc[3][0] += a4.w * w4.x; acc[3][1] += a4.w * w4.y; acc[3][2] += a4.w * w4.z; acc[3][3] += a4.w * w4.w;
        }
        __syncthreads();
    }
    const int bb = b0 + ty * 4, jj = j0 + tx * 4;
    #pragma unroll
    for (int r = 0; r < 4; ++r)
        #pragma unroll
        for (int c = 0; c < 4; ++c)
            out[(size_t)(bb + r) * 8192 + (size_t)(jj + c) * 32 + u] = acc[r][c];
}

__global__ __launch_bounds__(256) void arma_assemble2(
    const float* __restrict__ state,
    const float* __restrict__ out,
    float* __restrict__ out_state)
{
    const size_t i = (size_t)blockIdx.x * 256 + threadIdx.x;
    const f32x4 o = *(const f32x4*)(out + i * 4);
    const float* sp = state + i * 16;
    const f32x4 s0 = *(const f32x4*)(sp + 0);
    const f32x4 s1 = *(const f32x4*)(sp + 4);
    const f32x4 s2 = *(const f32x4*)(sp + 8);
    const f32x4 s3 = *(const f32x4*)(sp + 12);
    f32x4 r0 = { o[0], s0[0], s0[1], s0[2] };
    f32x4 r1 = { o[1], s1[0], s1[1], s1[2] };
    f32x4 r2 = { o[2], s2[0], s2[1], s2[2] };
    f32x4 r3 = { o[3], s3[0], s3[1], s3[2] };
    f32x4* dp = (f32x4*)(out_state + i * 16);
    __builtin_nontemporal_store(r0, dp + 0);
    __builtin_nontemporal_store(r1, dp + 1);
    __builtin_nontemporal_store(r2, dp + 2);
    __builtin_nontemporal_store(r3, dp + 3);
}

extern "C" void kernel_launch(void* const* d_in, const int* in_sizes, int n_in,
                              void* d_out, int out_size, void* d_ws, size_t ws_size,
                              hipStream_t stream) {
    const float* inputs = (const float*)d_in[0];
    const float* state  = (const float*)d_in[1];
    const float* kern   = (const float*)d_in[2];
    const float* rkern  = (const float*)d_in[3];

    float* out       = (float*)d_out;
    float* out_state = (float*)d_out + 8388608;

    const size_t WTT_BYTES  = (size_t)32 * 2 * 64 * 128 * 32 * 2;      // 33,554,432
    const size_t ATAR_BYTES = (size_t)16 * 32 * 64 * 32 * 2;           //  2,097,152
    const size_t CT_BYTES   = (size_t)32 * 1024 * 256 * 4;             // 33,554,432
    const size_t R6_BYTES   = WTT_BYTES + ATAR_BYTES + CT_BYTES;       // 69,206,016

    if (ws_size >= R6_BYTES) {
        unsigned short* Wtt   = (unsigned short*)d_ws;
        unsigned short* At_ar = (unsigned short*)((char*)d_ws + WTT_BYTES);
        float* Ct             = (float*)((char*)d_ws + WTT_BYTES + ATAR_BYTES);
        prep_all<<<dim3(4608), 256, 0, stream>>>(kern, rkern, inputs, Wtt, At_ar);
        arma_gemm_mfma3<<<dim3(1024), 256, 0, stream>>>(At_ar, state, Wtt, Ct);
        arma_assemble3<<<dim3(1024), 256, 0, stream>>>(state, Ct, out, out_state);
    } else {
        arma_gemm_f32<<<dim3(16, 4, 32), 256, 0, stream>>>(inputs, state, kern, rkern, out);
        arma_assemble2<<<8388608 / 4 / 256, 256, 0, stream>>>(state, out, out_state);
    }
}